// Round 11
// baseline (525.575 us; speedup 1.0000x reference)
//
#include <hip/hip_runtime.h>

// SINDy: out[65536,32] = Theta(z)[65536,6545] @ (Xi*Xi_mask)[6545,32]
// Round-11 = R9 (best, 70.5us) + two quantified fixes:
//  - split-K x8: 8192 waves -> 8 waves/SIMD (R9's grid capped it at 4).
//    Block = 512 thr = 8 waves = one tile-pair x 8 k-ranges of 70 chunks
//    (schedule padded 552->560; pads have B=0). LDS 21KB: cs shrunk to
//    2x32x32 via sequential-add combine (7 syncs).
//  - 1-inst truncation pack (v_perm hi16 pairs, no round adds): -16 inst/iter
//    and shorter A-fragment dependency tail. bf16 trunc err <= 1ulp -> absmax
//    ~8 vs threshold 19.76.
// Inner loop/pipeline IDENTICAL to R9 (proven: VGPR 60, no scratch).
// MFMA 32x32x16_bf16 layouts (verified rounds 1-10):
//   A[m][k]: m=lane&31, k=(lane>>5)*8+jj
//   B[k][n]: n=lane&31, k=(lane>>5)*8+jj
//   C/D:     col=lane&31, row=(reg&3)+8*(reg>>2)+4*(lane>>5)

#define Z 32
#define ROWS 65536
#define NBLK (ROWS / 64)         // 1024 blocks: 2 tiles x 8 k-splits (8 waves)

#define NCHUNK 560               // quarters: 36 + 84 + 160 + 280 (Q3 padded)
#define NGRAN (NCHUNK * 2)
#define NGP 1136                 // padded mg table (pipeline overreads -> 0)
#define KSPAN 70                 // chunks per k-split (560/8)

typedef short short8 __attribute__((ext_vector_type(8)));
typedef float f32x16 __attribute__((ext_vector_type(16)));
typedef float float2v __attribute__((ext_vector_type(2)));

struct Sched {
    unsigned mg[NGP];          // (i*128) | (j*128)<<16 byte offs into col-major zs; pad=0
    short rt[NGRAN * 8];       // library row per (granule, jj), -1 = pad
    int nq[4];
};

constexpr Sched make_sched() {
    Sched s{};
    short gi[NGRAN] = {}, gj[NGRAN] = {};
    char gt[NGRAN] = {}, gq[NGRAN] = {};
    int tidx[32][32] = {}, pidx[32] = {};
    {
        int n = 0;
        for (int a = 0; a < 32; ++a)
            for (int b = a; b < 32; ++b) { tidx[a][b] = n; n += 32 - b; }
        for (int i = 0; i < 32; ++i) pidx[i] = i * 32 - i * (i - 1) / 2;
    }
    int g = 0;
    for (int q = 0; q < 4; ++q) {
        int g0 = g;
        // triples (a<=b): granule covers k in [8q,8q+8) for k>=b -> b>>3 <= q
        for (int b = 0; b < 32; ++b)
            if ((b >> 3) <= q)
                for (int a = 0; a <= b; ++a) { gi[g]=(short)a; gj[g]=(short)b; gt[g]=0; gq[g]=(char)q; ++g; }
        // pairs (b,32): theta = z_b*z_k, valid k<=b -> b>>3 >= q
        for (int b = 0; b < 32; ++b)
            if ((b >> 3) >= q) { gi[g]=(short)b; gj[g]=32; gt[g]=1; gq[g]=(char)q; ++g; }
        // linear: theta = z_k
        gi[g]=32; gj[g]=32; gt[g]=2; gq[g]=(char)q; ++g;
        // pad quarter to a multiple of 8 granules (4 chunks)
        while ((g - g0) & 7) { gi[g]=32; gj[g]=32; gt[g]=3; gq[g]=(char)q; ++g; }
        // Q3: extra pad to 560 granules (280 chunks) for the x8 split
        if (q == 3)
            while ((g - g0) < 560) { gi[g]=32; gj[g]=32; gt[g]=3; gq[g]=(char)q; ++g; }
        s.nq[q] = (g - g0) / 2;
    }
    for (int gg = 0; gg < NGRAN; ++gg) {
        s.mg[gg] = ((unsigned)gi[gg] * 128u) | (((unsigned)gj[gg] * 128u) << 16);
        int i = gi[gg], j = gj[gg], ty = gt[gg], q = gq[gg];
        for (int jj = 0; jj < 8; ++jj) {
            int k = 8 * q + jj, row = -1;
            if (ty == 0)      { if (k >= j) row = 561 + tidx[i][j] + (k - j); }   // triple (i,j,k)
            else if (ty == 1) { if (k <= i) row = 33 + pidx[k] + (i - k); }       // pair (k,i)
            else if (ty == 2) { row = 1 + k; }                                    // linear z_k
            s.rt[gg * 8 + jj] = (short)row;
        }
    }
    // mg[NGRAN..NGP) stays 0 -> pipeline overreads hit zs[0][m], never used
    return s;
}
constexpr Sched S = make_sched();
static_assert(S.nq[0] == 36 && S.nq[1] == 84 && S.nq[2] == 160 && S.nq[3] == 280, "chunk counts");

// truncation pack: out = hi16(s0) | hi16(s1)<<16 — one v_perm, no adds
__device__ __forceinline__ unsigned pack_bf16(float s0, float s1) {
    return __builtin_amdgcn_perm(__builtin_bit_cast(unsigned, s1),
                                 __builtin_bit_cast(unsigned, s0), 0x07060302u);
}

// ---- prep (R7-proven): coalesced, block per 4 granules; B bf16 stays RNE ----
__global__ void sindy_prep(const float* __restrict__ Xi,
                           const float* __restrict__ Xi_mask,
                           uint2* __restrict__ Bp2, size_t ws_size) {
    __shared__ unsigned short sh[8][32];
    const int tid = threadIdx.x;
    const int jj = tid >> 5, n = tid & 31;
#pragma unroll
    for (int pass = 0; pass < 4; ++pass) {
        int g = blockIdx.x * 4 + pass;
        int row = S.rt[g * 8 + jj];
        float f = 0.0f;
        if (row >= 0) f = Xi[row * Z + n] * Xi_mask[row * Z + n];
        unsigned u = __builtin_bit_cast(unsigned, f);
        sh[jj][n] = (unsigned short)((u + 0x7FFFu + ((u >> 16) & 1u)) >> 16);  // RNE
        __syncthreads();
        if (tid < 64) {
            int n2 = tid & 31, rep = tid >> 5;
            unsigned v0 = sh[4*rep+0][n2], v1 = sh[4*rep+1][n2];
            unsigned v2 = sh[4*rep+2][n2], v3 = sh[4*rep+3][n2];
            int c = g >> 1, h = g & 1;
            size_t idx = ((size_t)c * 64 + h * 32 + n2) * 2 + rep;
            if ((idx + 1) * 8 <= ws_size)
                Bp2[idx] = uint2{v0 | (v1 << 16), v2 | (v3 << 16)};
        }
        __syncthreads();
    }
}

// ---- main: block = 512 thr = 8 waves; wave = BOTH tiles, one 70-chunk k-range ----
__global__ __launch_bounds__(512, 8) void sindy_mfma(const float* __restrict__ z,
                                                     const float* __restrict__ Xi,
                                                     const float* __restrict__ Xi_mask,
                                                     const uint4* __restrict__ Bp,
                                                     float* __restrict__ out) {
    const int lane = threadIdx.x & 63;
    const int kh = threadIdx.x >> 6;     // k-split 0..7
    const int m = lane & 31;
    const int half = lane >> 5;
    const long R = (long)blockIdx.x * 64;   // rows of tile0; tile1 = R+32

    __shared__ float zs[2][33][32];      // col-major zs[t][k][m]; bank = m
    __shared__ float cs[2][32][32];      // sequential-add combine buffer
    __shared__ unsigned mg_sh[NGP];

    for (int t = threadIdx.x; t < NGP; t += 512) mg_sh[t] = S.mg[t];
    // stage z for 64 rows (one coalesced float4 per thread)
    {
        int idx = threadIdx.x;
        int row = idx >> 3, q4 = idx & 7;
        float4 v = ((const float4*)(z + (R + row) * Z))[q4];
        int t = row >> 5, mm = row & 31;
        zs[t][4*q4+0][mm] = v.x; zs[t][4*q4+1][mm] = v.y;
        zs[t][4*q4+2][mm] = v.z; zs[t][4*q4+3][mm] = v.w;
    }
    if (threadIdx.x < 64) zs[threadIdx.x >> 5][32][threadIdx.x & 31] = 1.0f;  // z~[32]=1
    __syncthreads();

    const int c0 = kh * KSPAN;
    const char* zmb0 = (const char*)&zs[0][0][0] + 4 * m;
    const char* zmb1 = (const char*)&zs[1][0][0] + 4 * m;
    const unsigned* mgh = mg_sh + half;

    const uint4* p = Bp + lane + (size_t)c0 * 64;
    uint4 curA = p[0], curB = p[64];

    // prime shallow pipeline (plain scalars, single scope — R9-proven)
    unsigned u0 = mgh[2*c0], u1 = mgh[2*c0+2];
    float pA0 = (*(const float*)(zmb0 + (u0 & 0xFFFFu))) * (*(const float*)(zmb0 + (u0 >> 16)));
    float pA1 = (*(const float*)(zmb1 + (u0 & 0xFFFFu))) * (*(const float*)(zmb1 + (u0 >> 16)));
    float pB0 = (*(const float*)(zmb0 + (u1 & 0xFFFFu))) * (*(const float*)(zmb0 + (u1 >> 16)));
    float pB1 = (*(const float*)(zmb1 + (u1 & 0xFFFFu))) * (*(const float*)(zmb1 + (u1 >> 16)));
    unsigned w0s = mgh[2*c0+4], w1s = mgh[2*c0+6];

    f32x16 acc0 = {}, acc1 = {};

    auto seg = [&](int Q, int cbeg, int cfin, bool lastp) {
        // this quarter's z octets for both tiles
        const char* zq0 = zmb0 + Q * 1024;
        const char* zq1 = zmb1 + Q * 1024;
        float2v zA0, zA1, zA2, zA3, zB0, zB1, zB2, zB3;
        zA0.x = *(const float*)(zq0 +   0); zA0.y = *(const float*)(zq0 + 128);
        zA1.x = *(const float*)(zq0 + 256); zA1.y = *(const float*)(zq0 + 384);
        zA2.x = *(const float*)(zq0 + 512); zA2.y = *(const float*)(zq0 + 640);
        zA3.x = *(const float*)(zq0 + 768); zA3.y = *(const float*)(zq0 + 896);
        zB0.x = *(const float*)(zq1 +   0); zB0.y = *(const float*)(zq1 + 128);
        zB1.x = *(const float*)(zq1 + 256); zB1.y = *(const float*)(zq1 + 384);
        zB2.x = *(const float*)(zq1 + 512); zB2.y = *(const float*)(zq1 + 640);
        zB3.x = *(const float*)(zq1 + 768); zB3.y = *(const float*)(zq1 + 896);

        auto mfma0 = [&](float pp, const uint4& bv) {   // tile0
            float2v p2; p2.x = pp; p2.y = pp;
            union { unsigned u[4]; short8 sv; } a;
            float2v t0 = p2 * zA0; a.u[0] = pack_bf16(t0.x, t0.y);
            float2v t1 = p2 * zA1; a.u[1] = pack_bf16(t1.x, t1.y);
            float2v t2 = p2 * zA2; a.u[2] = pack_bf16(t2.x, t2.y);
            float2v t3 = p2 * zA3; a.u[3] = pack_bf16(t3.x, t3.y);
            union { uint4 v; short8 sv; } b; b.v = bv;
            acc0 = __builtin_amdgcn_mfma_f32_32x32x16_bf16(a.sv, b.sv, acc0, 0, 0, 0);
        };
        auto mfma1 = [&](float pp, const uint4& bv) {   // tile1
            float2v p2; p2.x = pp; p2.y = pp;
            union { unsigned u[4]; short8 sv; } a;
            float2v t0 = p2 * zB0; a.u[0] = pack_bf16(t0.x, t0.y);
            float2v t1 = p2 * zB1; a.u[1] = pack_bf16(t1.x, t1.y);
            float2v t2 = p2 * zB2; a.u[2] = pack_bf16(t2.x, t2.y);
            float2v t3 = p2 * zB3; a.u[3] = pack_bf16(t3.x, t3.y);
            union { uint4 v; short8 sv; } b; b.v = bv;
            acc1 = __builtin_amdgcn_mfma_f32_32x32x16_bf16(a.sv, b.sv, acc1, 0, 0, 0);
        };

        for (int c = cbeg; c < cfin; c += 2) {
            // stage 1: mg for iter+2 (pad absorbs overread)
            unsigned nw0 = mgh[2*c+8], nw1 = mgh[2*c+10];
            // stage 2: z reads for iter+1 from staged words
            float a0i = *(const float*)(zmb0 + (w0s & 0xFFFFu)), a0j = *(const float*)(zmb0 + (w0s >> 16));
            float a1i = *(const float*)(zmb1 + (w0s & 0xFFFFu)), a1j = *(const float*)(zmb1 + (w0s >> 16));
            float b0i = *(const float*)(zmb0 + (w1s & 0xFFFFu)), b0j = *(const float*)(zmb0 + (w1s >> 16));
            float b1i = *(const float*)(zmb1 + (w1s & 0xFFFFu)), b1j = *(const float*)(zmb1 + (w1s >> 16));
            // stage 3: B prefetch (shared by both tiles)
            int off = (lastp && c + 2 >= cfin) ? 0 : 128;
            uint4 nA = p[off], nB = p[off + 64];
            // 4 MFMAs: 2 chunks x 2 tiles, B shared per chunk
            mfma0(pA0, curA); mfma1(pA1, curA);
            mfma0(pB0, curB); mfma1(pB1, curB);
            // retire
            pA0 = a0i * a0j; pA1 = a1i * a1j; pB0 = b0i * b0j; pB1 = b1i * b1j;
            w0s = nw0; w1s = nw1; curA = nA; curB = nB; p += off;
        }
    };

    // quarter-aligned pieces of this wave's [c0, c0+70) range
    if (kh == 0)      { seg(0,   0,  36, false); seg(1,  36,  70, true); }
    else if (kh == 1) { seg(1,  70, 120, false); seg(2, 120, 140, true); }
    else if (kh == 2) { seg(2, 140, 210, true); }
    else if (kh == 3) { seg(2, 210, 280, true); }
    else if (kh == 4) { seg(3, 280, 350, true); }
    else if (kh == 5) { seg(3, 350, 420, true); }
    else if (kh == 6) { seg(3, 420, 490, true); }
    else              { seg(3, 490, 560, true); }

    // sequential-add combine: kh1 writes, kh2..7 accumulate, kh0 finishes
    for (int t = 1; t < 8; ++t) {
        if (kh == t) {
#pragma unroll
            for (int r = 0; r < 16; ++r) {
                int row = (r & 3) + 8 * (r >> 2) + 4 * half;
                if (t == 1) { cs[0][row][m] = acc0[r];  cs[1][row][m] = acc1[r]; }
                else        { cs[0][row][m] += acc0[r]; cs[1][row][m] += acc1[r]; }
            }
        }
        __syncthreads();
    }
    if (kh == 0) {
        const float bias = Xi[m] * Xi_mask[m];   // library row 0 (ones), col n = m
        float* o0 = out + R * Z;
        float* o1 = out + (R + 32) * Z;
#pragma unroll
        for (int r = 0; r < 16; ++r) {
            int row = (r & 3) + 8 * (r >> 2) + 4 * half;
            o0[row * Z + m] = acc0[r] + cs[0][row][m] + bias;
            o1[row * Z + m] = acc1[r] + cs[1][row][m] + bias;
        }
    }
}

extern "C" void kernel_launch(void* const* d_in, const int* in_sizes, int n_in,
                              void* d_out, int out_size, void* d_ws, size_t ws_size,
                              hipStream_t stream) {
    const float* z       = (const float*)d_in[0];
    const float* Xi      = (const float*)d_in[1];
    const float* Xi_mask = (const float*)d_in[2];
    // d_in[3]=z_mean, d_in[4]=z_std: unused by the reference
    float* out = (float*)d_out;
    uint4* Bp  = (uint4*)d_ws;   // NCHUNK*64*16 = 573,440 bytes

    sindy_prep<<<NGRAN / 4, 256, 0, stream>>>(Xi, Xi_mask, (uint2*)d_ws, ws_size);
    sindy_mfma<<<NBLK, 512, 0, stream>>>(z, Xi, Xi_mask, Bp, out);
}

// Round 12
// 138.986 us; speedup vs baseline: 3.7815x; 3.7815x over previous
//
#include <hip/hip_runtime.h>

// SINDy: out[65536,32] = Theta(z)[65536,6545] @ (Xi*Xi_mask)[6545,32]
// Round-12 = R9 (best, 70.5us) with the iteration widened to 4 chunks x
// 2 tiles = 8 MFMAs (512 cyc issue) per iteration:
//  - B prefetch slack 256 -> 512 cyc (> L2 latency: kills the ~230 cyc/iter
//    bubble that matched L2 latency in R9's accounting)
//  - loop/stage overhead amortized over 2x the MFMAs
//  - 1-inst truncation pack (R11 proved absmax unchanged at 4.0)
//  - schedule padded 552->560 (Q3->280), KSPAN 140: all piece lengths %4
// All pipeline state = plain named scalars in ONE scope (R4/R8/R11 spill
// lesson); launch_bounds(256,4) -> cap 128 regs, est ~122 used.
// MFMA 32x32x16_bf16 layouts (verified rounds 1-11):
//   A[m][k]: m=lane&31, k=(lane>>5)*8+jj
//   B[k][n]: n=lane&31, k=(lane>>5)*8+jj
//   C/D:     col=lane&31, row=(reg&3)+8*(reg>>2)+4*(lane>>5)

#define Z 32
#define ROWS 65536
#define NBLK (ROWS / 64)         // 1024 blocks: 2 tiles x 4 k-splits (4 waves)

#define NCHUNK 560               // quarters: 36 + 84 + 160 + 280 (Q3 padded)
#define NGRAN (NCHUNK * 2)
#define NGP 1152                 // padded mg table (pipeline overreads -> 0)
#define KSPAN 140                // chunks per k-split (560/4)

typedef short short8 __attribute__((ext_vector_type(8)));
typedef float f32x16 __attribute__((ext_vector_type(16)));
typedef float float2v __attribute__((ext_vector_type(2)));

struct Sched {
    unsigned mg[NGP];          // (i*128) | (j*128)<<16 byte offs into col-major zs; pad=0
    short rt[NGRAN * 8];       // library row per (granule, jj), -1 = pad
    int nq[4];
};

constexpr Sched make_sched() {
    Sched s{};
    short gi[NGRAN] = {}, gj[NGRAN] = {};
    char gt[NGRAN] = {}, gq[NGRAN] = {};
    int tidx[32][32] = {}, pidx[32] = {};
    {
        int n = 0;
        for (int a = 0; a < 32; ++a)
            for (int b = a; b < 32; ++b) { tidx[a][b] = n; n += 32 - b; }
        for (int i = 0; i < 32; ++i) pidx[i] = i * 32 - i * (i - 1) / 2;
    }
    int g = 0;
    for (int q = 0; q < 4; ++q) {
        int g0 = g;
        // triples (a<=b): granule covers k in [8q,8q+8) for k>=b -> b>>3 <= q
        for (int b = 0; b < 32; ++b)
            if ((b >> 3) <= q)
                for (int a = 0; a <= b; ++a) { gi[g]=(short)a; gj[g]=(short)b; gt[g]=0; gq[g]=(char)q; ++g; }
        // pairs (b,32): theta = z_b*z_k, valid k<=b -> b>>3 >= q
        for (int b = 0; b < 32; ++b)
            if ((b >> 3) >= q) { gi[g]=(short)b; gj[g]=32; gt[g]=1; gq[g]=(char)q; ++g; }
        // linear: theta = z_k
        gi[g]=32; gj[g]=32; gt[g]=2; gq[g]=(char)q; ++g;
        // pad quarter to a multiple of 8 granules (4 chunks)
        while ((g - g0) & 7) { gi[g]=32; gj[g]=32; gt[g]=3; gq[g]=(char)q; ++g; }
        // Q3: extra pad to 560 granules (280 chunks) for the KSPAN=140 split
        if (q == 3)
            while ((g - g0) < 560) { gi[g]=32; gj[g]=32; gt[g]=3; gq[g]=(char)q; ++g; }
        s.nq[q] = (g - g0) / 2;
    }
    for (int gg = 0; gg < NGRAN; ++gg) {
        s.mg[gg] = ((unsigned)gi[gg] * 128u) | (((unsigned)gj[gg] * 128u) << 16);
        int i = gi[gg], j = gj[gg], ty = gt[gg], q = gq[gg];
        for (int jj = 0; jj < 8; ++jj) {
            int k = 8 * q + jj, row = -1;
            if (ty == 0)      { if (k >= j) row = 561 + tidx[i][j] + (k - j); }   // triple (i,j,k)
            else if (ty == 1) { if (k <= i) row = 33 + pidx[k] + (i - k); }       // pair (k,i)
            else if (ty == 2) { row = 1 + k; }                                    // linear z_k
            s.rt[gg * 8 + jj] = (short)row;
        }
    }
    // mg[NGRAN..NGP) stays 0 -> pipeline overreads hit zs sentinel region, unused
    return s;
}
constexpr Sched S = make_sched();
static_assert(S.nq[0] == 36 && S.nq[1] == 84 && S.nq[2] == 160 && S.nq[3] == 280, "chunk counts");

// truncation pack: out = hi16(s0) | hi16(s1)<<16 — one v_perm (R11-proven numerics)
__device__ __forceinline__ unsigned pack_bf16(float s0, float s1) {
    return __builtin_amdgcn_perm(__builtin_bit_cast(unsigned, s1),
                                 __builtin_bit_cast(unsigned, s0), 0x07060302u);
}

// ---- prep (R7-proven): coalesced, block per 4 granules; B bf16 stays RNE ----
__global__ void sindy_prep(const float* __restrict__ Xi,
                           const float* __restrict__ Xi_mask,
                           uint2* __restrict__ Bp2, size_t ws_size) {
    __shared__ unsigned short sh[8][32];
    const int tid = threadIdx.x;
    const int jj = tid >> 5, n = tid & 31;
#pragma unroll
    for (int pass = 0; pass < 4; ++pass) {
        int g = blockIdx.x * 4 + pass;
        int row = S.rt[g * 8 + jj];
        float f = 0.0f;
        if (row >= 0) f = Xi[row * Z + n] * Xi_mask[row * Z + n];
        unsigned u = __builtin_bit_cast(unsigned, f);
        sh[jj][n] = (unsigned short)((u + 0x7FFFu + ((u >> 16) & 1u)) >> 16);  // RNE
        __syncthreads();
        if (tid < 64) {
            int n2 = tid & 31, rep = tid >> 5;
            unsigned v0 = sh[4*rep+0][n2], v1 = sh[4*rep+1][n2];
            unsigned v2 = sh[4*rep+2][n2], v3 = sh[4*rep+3][n2];
            int c = g >> 1, h = g & 1;
            size_t idx = ((size_t)c * 64 + h * 32 + n2) * 2 + rep;
            if ((idx + 1) * 8 <= ws_size)
                Bp2[idx] = uint2{v0 | (v1 << 16), v2 | (v3 << 16)};
        }
        __syncthreads();
    }
}

// ---- main: block = 2 tiles x 4 k-splits; wave = BOTH tiles, one 140-chunk range ----
__global__ __launch_bounds__(256, 4) void sindy_mfma(const float* __restrict__ z,
                                                     const float* __restrict__ Xi,
                                                     const float* __restrict__ Xi_mask,
                                                     const uint4* __restrict__ Bp,
                                                     float* __restrict__ out) {
    const int lane = threadIdx.x & 63;
    const int kh = threadIdx.x >> 6;     // k-split 0..3
    const int m = lane & 31;
    const int half = lane >> 5;
    const long R = (long)blockIdx.x * 64;   // rows of tile0; tile1 = R+32

    __shared__ float zs[2][33][32];      // col-major zs[t][k][m]; bank = m
    __shared__ float cs[3][2][32][32];   // partials from kh1..3, per tile
    __shared__ unsigned mg_sh[NGP];

    for (int t = threadIdx.x; t < NGP; t += 256) mg_sh[t] = S.mg[t];
    // stage z for 64 rows (coalesced float4 reads)
    for (int idx = threadIdx.x; idx < 512; idx += 256) {
        int row = idx >> 3, q4 = idx & 7;
        float4 v = ((const float4*)(z + (R + row) * Z))[q4];
        int t = row >> 5, mm = row & 31;
        zs[t][4*q4+0][mm] = v.x; zs[t][4*q4+1][mm] = v.y;
        zs[t][4*q4+2][mm] = v.z; zs[t][4*q4+3][mm] = v.w;
    }
    if (threadIdx.x < 64) zs[threadIdx.x >> 5][32][threadIdx.x & 31] = 1.0f;  // z~[32]=1
    __syncthreads();

    const int c0 = kh * KSPAN;
    const char* zmb0 = (const char*)&zs[0][0][0] + 4 * m;
    const char* zmb1 = (const char*)&zs[1][0][0] + 4 * m;
    const unsigned* mgh = mg_sh + half;

    const uint4* p = Bp + lane + (size_t)c0 * 64;
    uint4 curA = p[0], curB = p[64], curC = p[128], curD = p[192];

    // prime pipeline (plain scalars, single scope — R9-proven pattern)
    unsigned u;
    u = mgh[2*(c0+0)];
    float pA0 = (*(const float*)(zmb0 + (u & 0xFFFFu))) * (*(const float*)(zmb0 + (u >> 16)));
    float pA1 = (*(const float*)(zmb1 + (u & 0xFFFFu))) * (*(const float*)(zmb1 + (u >> 16)));
    u = mgh[2*(c0+1)];
    float pB0 = (*(const float*)(zmb0 + (u & 0xFFFFu))) * (*(const float*)(zmb0 + (u >> 16)));
    float pB1 = (*(const float*)(zmb1 + (u & 0xFFFFu))) * (*(const float*)(zmb1 + (u >> 16)));
    u = mgh[2*(c0+2)];
    float pC0 = (*(const float*)(zmb0 + (u & 0xFFFFu))) * (*(const float*)(zmb0 + (u >> 16)));
    float pC1 = (*(const float*)(zmb1 + (u & 0xFFFFu))) * (*(const float*)(zmb1 + (u >> 16)));
    u = mgh[2*(c0+3)];
    float pD0 = (*(const float*)(zmb0 + (u & 0xFFFFu))) * (*(const float*)(zmb0 + (u >> 16)));
    float pD1 = (*(const float*)(zmb1 + (u & 0xFFFFu))) * (*(const float*)(zmb1 + (u >> 16)));
    unsigned w0 = mgh[2*(c0+4)], w1 = mgh[2*(c0+5)], w2 = mgh[2*(c0+6)], w3 = mgh[2*(c0+7)];

    f32x16 acc0 = {}, acc1 = {};

    auto seg = [&](int Q, int cbeg, int cfin, bool lastp) {
        // this quarter's z octets for both tiles
        const char* zq0 = zmb0 + Q * 1024;
        const char* zq1 = zmb1 + Q * 1024;
        float2v zA0, zA1, zA2, zA3, zB0, zB1, zB2, zB3;
        zA0.x = *(const float*)(zq0 +   0); zA0.y = *(const float*)(zq0 + 128);
        zA1.x = *(const float*)(zq0 + 256); zA1.y = *(const float*)(zq0 + 384);
        zA2.x = *(const float*)(zq0 + 512); zA2.y = *(const float*)(zq0 + 640);
        zA3.x = *(const float*)(zq0 + 768); zA3.y = *(const float*)(zq0 + 896);
        zB0.x = *(const float*)(zq1 +   0); zB0.y = *(const float*)(zq1 + 128);
        zB1.x = *(const float*)(zq1 + 256); zB1.y = *(const float*)(zq1 + 384);
        zB2.x = *(const float*)(zq1 + 512); zB2.y = *(const float*)(zq1 + 640);
        zB3.x = *(const float*)(zq1 + 768); zB3.y = *(const float*)(zq1 + 896);

        auto mfma0 = [&](float pp, const uint4& bv) {   // tile0
            float2v p2; p2.x = pp; p2.y = pp;
            union { unsigned u[4]; short8 sv; } a;
            float2v t0 = p2 * zA0; a.u[0] = pack_bf16(t0.x, t0.y);
            float2v t1 = p2 * zA1; a.u[1] = pack_bf16(t1.x, t1.y);
            float2v t2 = p2 * zA2; a.u[2] = pack_bf16(t2.x, t2.y);
            float2v t3 = p2 * zA3; a.u[3] = pack_bf16(t3.x, t3.y);
            union { uint4 v; short8 sv; } b; b.v = bv;
            acc0 = __builtin_amdgcn_mfma_f32_32x32x16_bf16(a.sv, b.sv, acc0, 0, 0, 0);
        };
        auto mfma1 = [&](float pp, const uint4& bv) {   // tile1
            float2v p2; p2.x = pp; p2.y = pp;
            union { unsigned u[4]; short8 sv; } a;
            float2v t0 = p2 * zB0; a.u[0] = pack_bf16(t0.x, t0.y);
            float2v t1 = p2 * zB1; a.u[1] = pack_bf16(t1.x, t1.y);
            float2v t2 = p2 * zB2; a.u[2] = pack_bf16(t2.x, t2.y);
            float2v t3 = p2 * zB3; a.u[3] = pack_bf16(t3.x, t3.y);
            union { uint4 v; short8 sv; } b; b.v = bv;
            acc1 = __builtin_amdgcn_mfma_f32_32x32x16_bf16(a.sv, b.sv, acc1, 0, 0, 0);
        };

        for (int c = cbeg; c < cfin; c += 4) {
            // stage 1: mg words for chunks c+8..c+11 (pad absorbs overread)
            unsigned nw0 = mgh[2*c+16], nw1 = mgh[2*c+18], nw2 = mgh[2*c+20], nw3 = mgh[2*c+22];
            // stage 2: z reads for chunks c+4..c+7 from staged words
            float a0i = *(const float*)(zmb0 + (w0 & 0xFFFFu)), a0j = *(const float*)(zmb0 + (w0 >> 16));
            float a1i = *(const float*)(zmb1 + (w0 & 0xFFFFu)), a1j = *(const float*)(zmb1 + (w0 >> 16));
            float e0i = *(const float*)(zmb0 + (w1 & 0xFFFFu)), e0j = *(const float*)(zmb0 + (w1 >> 16));
            float e1i = *(const float*)(zmb1 + (w1 & 0xFFFFu)), e1j = *(const float*)(zmb1 + (w1 >> 16));
            float g0i = *(const float*)(zmb0 + (w2 & 0xFFFFu)), g0j = *(const float*)(zmb0 + (w2 >> 16));
            float g1i = *(const float*)(zmb1 + (w2 & 0xFFFFu)), g1j = *(const float*)(zmb1 + (w2 >> 16));
            float h0i = *(const float*)(zmb0 + (w3 & 0xFFFFu)), h0j = *(const float*)(zmb0 + (w3 >> 16));
            float h1i = *(const float*)(zmb1 + (w3 & 0xFFFFu)), h1j = *(const float*)(zmb1 + (w3 >> 16));
            // stage 3: B prefetch for chunks c+4..c+7 (shared by both tiles)
            int off = (lastp && c + 4 >= cfin) ? 0 : 256;
            uint4 nA = p[off], nB = p[off + 64], nC = p[off + 128], nD = p[off + 192];
            // 8 MFMAs: 4 chunks x 2 tiles, B shared per chunk (512 cyc issue)
            mfma0(pA0, curA); mfma1(pA1, curA);
            mfma0(pB0, curB); mfma1(pB1, curB);
            mfma0(pC0, curC); mfma1(pC1, curC);
            mfma0(pD0, curD); mfma1(pD1, curD);
            // retire
            pA0 = a0i * a0j; pA1 = a1i * a1j; pB0 = e0i * e0j; pB1 = e1i * e1j;
            pC0 = g0i * g0j; pC1 = g1i * g1j; pD0 = h0i * h0j; pD1 = h1i * h1j;
            w0 = nw0; w1 = nw1; w2 = nw2; w3 = nw3;
            curA = nA; curB = nB; curC = nC; curD = nD;
            p += off;
        }
    };

    // quarter-aligned pieces of this wave's [c0, c0+140) range (all %4 == 0)
    if (kh == 0)      { seg(0,   0,  36, false); seg(1,  36, 120, false); seg(2, 120, 140, true); }
    else if (kh == 1) { seg(2, 140, 280, true); }
    else if (kh == 2) { seg(3, 280, 420, true); }
    else              { seg(3, 420, 560, true); }

    // combine: kh1..3 park partials; kh0 reduces + stores both tiles
    if (kh != 0) {
#pragma unroll
        for (int r = 0; r < 16; ++r) {
            int row = (r & 3) + 8 * (r >> 2) + 4 * half;
            cs[kh - 1][0][row][m] = acc0[r];
            cs[kh - 1][1][row][m] = acc1[r];
        }
    }
    __syncthreads();
    if (kh == 0) {
        const float bias = Xi[m] * Xi_mask[m];   // library row 0 (ones), col n = m
        float* o0 = out + R * Z;
        float* o1 = out + (R + 32) * Z;
#pragma unroll
        for (int r = 0; r < 16; ++r) {
            int row = (r & 3) + 8 * (r >> 2) + 4 * half;
            o0[row * Z + m] = acc0[r] + cs[0][0][row][m] + cs[1][0][row][m] + cs[2][0][row][m] + bias;
            o1[row * Z + m] = acc1[r] + cs[0][1][row][m] + cs[1][1][row][m] + cs[2][1][row][m] + bias;
        }
    }
}

extern "C" void kernel_launch(void* const* d_in, const int* in_sizes, int n_in,
                              void* d_out, int out_size, void* d_ws, size_t ws_size,
                              hipStream_t stream) {
    const float* z       = (const float*)d_in[0];
    const float* Xi      = (const float*)d_in[1];
    const float* Xi_mask = (const float*)d_in[2];
    // d_in[3]=z_mean, d_in[4]=z_std: unused by the reference
    float* out = (float*)d_out;
    uint4* Bp  = (uint4*)d_ws;   // NCHUNK*64*16 = 573,440 bytes

    sindy_prep<<<NGRAN / 4, 256, 0, stream>>>(Xi, Xi_mask, (uint2*)d_ws, ws_size);
    sindy_mfma<<<NBLK, 256, 0, stream>>>(z, Xi, Xi_mask, Bp, out);
}

// Round 13
// 122.620 us; speedup vs baseline: 4.2862x; 1.1335x over previous
//
#include <hip/hip_runtime.h>

// SINDy: out[65536,32] = Theta(z)[65536,6545] @ (Xi*Xi_mask)[6545,32]
// Round-13 = R9 (best, 70.5us) + two ZERO-REGISTER-COST changes (the R9/R12
// pair proved arch-VGPR budget is hard-capped at 64 with 32 AGPRs @ 4 w/EU):
//  - B prefetch distance 2 iters via cur<-sh rotation with the load issued
//    AFTER the MFMA block straight into sh: live B-regs stay 16 (R9-equal),
//    slack ~350 -> ~650 cyc > loaded-L2 latency (R9's bubble theory).
//  - truncation pack (1 v_perm; R11 proved absmax unchanged at 4.0):
//    -8 VALU/iter, paying for the +8 v_mov of the rotation.
// Everything else byte-identical to R9.
// MFMA 32x32x16_bf16 layouts (verified rounds 1-12):
//   A[m][k]: m=lane&31, k=(lane>>5)*8+jj
//   B[k][n]: n=lane&31, k=(lane>>5)*8+jj
//   C/D:     col=lane&31, row=(reg&3)+8*(reg>>2)+4*(lane>>5)

#define Z 32
#define ROWS 65536
#define NBLK (ROWS / 64)         // 1024 blocks: 2 tiles x 4 k-splits (4 waves)

#define NCHUNK 552               // quarters: 36 + 84 + 160 + 272
#define NGRAN (NCHUNK * 2)
#define NGP 1120                 // padded mg table (overreads -> 0)
#define KSPAN 138                // chunks per k-split (552/4)

typedef short short8 __attribute__((ext_vector_type(8)));
typedef float f32x16 __attribute__((ext_vector_type(16)));
typedef float float2v __attribute__((ext_vector_type(2)));

struct Sched {
    unsigned mg[NGP];          // (i*128) | (j*128)<<16 byte offs into col-major zs; pad=0
    short rt[NGRAN * 8];       // library row per (granule, jj), -1 = pad
    int nq[4];
};

constexpr Sched make_sched() {
    Sched s{};
    short gi[NGP] = {}, gj[NGP] = {};
    char gt[NGP] = {}, gq[NGP] = {};
    int tidx[32][32] = {}, pidx[32] = {};
    {
        int n = 0;
        for (int a = 0; a < 32; ++a)
            for (int b = a; b < 32; ++b) { tidx[a][b] = n; n += 32 - b; }
        for (int i = 0; i < 32; ++i) pidx[i] = i * 32 - i * (i - 1) / 2;
    }
    int g = 0;
    for (int q = 0; q < 4; ++q) {
        int g0 = g;
        // triples (a<=b): granule covers k in [8q,8q+8) for k>=b -> b>>3 <= q
        for (int b = 0; b < 32; ++b)
            if ((b >> 3) <= q)
                for (int a = 0; a <= b; ++a) { gi[g]=(short)a; gj[g]=(short)b; gt[g]=0; gq[g]=(char)q; ++g; }
        // pairs (b,32): theta = z_b*z_k, valid k<=b -> b>>3 >= q
        for (int b = 0; b < 32; ++b)
            if ((b >> 3) >= q) { gi[g]=(short)b; gj[g]=32; gt[g]=1; gq[g]=(char)q; ++g; }
        // linear: theta = z_k
        gi[g]=32; gj[g]=32; gt[g]=2; gq[g]=(char)q; ++g;
        // pad quarter to a multiple of 8 granules (4 chunks)
        while ((g - g0) & 7) { gi[g]=32; gj[g]=32; gt[g]=3; gq[g]=(char)q; ++g; }
        s.nq[q] = (g - g0) / 2;
    }
    for (int gg = 0; gg < NGRAN; ++gg) {
        s.mg[gg] = ((unsigned)gi[gg] * 128u) | (((unsigned)gj[gg] * 128u) << 16);
        int i = gi[gg], j = gj[gg], ty = gt[gg], q = gq[gg];
        for (int jj = 0; jj < 8; ++jj) {
            int k = 8 * q + jj, row = -1;
            if (ty == 0)      { if (k >= j) row = 561 + tidx[i][j] + (k - j); }   // triple (i,j,k)
            else if (ty == 1) { if (k <= i) row = 33 + pidx[k] + (i - k); }       // pair (k,i)
            else if (ty == 2) { row = 1 + k; }                                    // linear z_k
            s.rt[gg * 8 + jj] = (short)row;
        }
    }
    // [NGRAN,NGP): mg stays 0 -> pipeline overreads hit zs[0][m], never used
    return s;
}
constexpr Sched S = make_sched();
static_assert(S.nq[0] == 36 && S.nq[1] == 84 && S.nq[2] == 160 && S.nq[3] == 272, "chunk counts");

// truncation pack: out = hi16(s0) | hi16(s1)<<16 — one v_perm (R11-proven numerics)
__device__ __forceinline__ unsigned pack_bf16(float s0, float s1) {
    return __builtin_amdgcn_perm(__builtin_bit_cast(unsigned, s1),
                                 __builtin_bit_cast(unsigned, s0), 0x07060302u);
}

// ---- prep (R7-proven): coalesced, block per 4 granules; B bf16 stays RNE ----
__global__ void sindy_prep(const float* __restrict__ Xi,
                           const float* __restrict__ Xi_mask,
                           uint2* __restrict__ Bp2, size_t ws_size) {
    __shared__ unsigned short sh[8][32];
    const int tid = threadIdx.x;
    const int jj = tid >> 5, n = tid & 31;
#pragma unroll
    for (int pass = 0; pass < 4; ++pass) {
        int g = blockIdx.x * 4 + pass;
        int row = S.rt[g * 8 + jj];
        float f = 0.0f;
        if (row >= 0) f = Xi[row * Z + n] * Xi_mask[row * Z + n];
        unsigned u = __builtin_bit_cast(unsigned, f);
        sh[jj][n] = (unsigned short)((u + 0x7FFFu + ((u >> 16) & 1u)) >> 16);  // RNE
        __syncthreads();
        if (tid < 64) {
            int n2 = tid & 31, rep = tid >> 5;
            unsigned v0 = sh[4*rep+0][n2], v1 = sh[4*rep+1][n2];
            unsigned v2 = sh[4*rep+2][n2], v3 = sh[4*rep+3][n2];
            int c = g >> 1, h = g & 1;
            size_t idx = ((size_t)c * 64 + h * 32 + n2) * 2 + rep;
            if ((idx + 1) * 8 <= ws_size)
                Bp2[idx] = uint2{v0 | (v1 << 16), v2 | (v3 << 16)};
        }
        __syncthreads();
    }
}

// ---- main: block = 2 tiles x 4 k-splits; wave = BOTH tiles, one k-split ----
__global__ __launch_bounds__(256, 4) void sindy_mfma(const float* __restrict__ z,
                                                     const float* __restrict__ Xi,
                                                     const float* __restrict__ Xi_mask,
                                                     const uint4* __restrict__ Bp,
                                                     float* __restrict__ out) {
    const int lane = threadIdx.x & 63;
    const int kh = threadIdx.x >> 6;     // k-split 0..3
    const int m = lane & 31;
    const int half = lane >> 5;
    const long R = (long)blockIdx.x * 64;   // rows of tile0; tile1 = R+32

    __shared__ float zs[2][33][32];      // col-major zs[t][k][m]; bank = m
    __shared__ float cs[3][2][32][32];   // partials from kh1..3, per tile
    __shared__ unsigned mg_sh[NGP];

    for (int t = threadIdx.x; t < NGP; t += 256) mg_sh[t] = S.mg[t];
    // stage z for 64 rows (coalesced float4 reads)
    for (int idx = threadIdx.x; idx < 512; idx += 256) {
        int row = idx >> 3, q4 = idx & 7;
        float4 v = ((const float4*)(z + (R + row) * Z))[q4];
        int t = row >> 5, mm = row & 31;
        zs[t][4*q4+0][mm] = v.x; zs[t][4*q4+1][mm] = v.y;
        zs[t][4*q4+2][mm] = v.z; zs[t][4*q4+3][mm] = v.w;
    }
    if (threadIdx.x < 64) zs[threadIdx.x >> 5][32][threadIdx.x & 31] = 1.0f;  // z~[32]=1
    __syncthreads();

    const int c0 = kh * KSPAN;
    const char* zmb0 = (const char*)&zs[0][0][0] + 4 * m;
    const char* zmb1 = (const char*)&zs[1][0][0] + 4 * m;
    const unsigned* mgh = mg_sh + half;

    // B stream: cur = chunks (c, c+1), sh = chunks (c+2, c+3); loads issued
    // after the MFMA block go straight into sh (distance 2, no extra regs)
    const uint4* p = Bp + lane + (size_t)c0 * 64;
    uint4 curA = p[0], curB = p[64];
    uint4 shA  = p[128], shB = p[192];

    // prime shallow pipeline (plain scalars, single scope — R9-proven)
    unsigned u0 = mgh[2*c0], u1 = mgh[2*c0+2];
    float pA0 = (*(const float*)(zmb0 + (u0 & 0xFFFFu))) * (*(const float*)(zmb0 + (u0 >> 16)));
    float pA1 = (*(const float*)(zmb1 + (u0 & 0xFFFFu))) * (*(const float*)(zmb1 + (u0 >> 16)));
    float pB0 = (*(const float*)(zmb0 + (u1 & 0xFFFFu))) * (*(const float*)(zmb0 + (u1 >> 16)));
    float pB1 = (*(const float*)(zmb1 + (u1 & 0xFFFFu))) * (*(const float*)(zmb1 + (u1 >> 16)));
    unsigned w0s = mgh[2*c0+4], w1s = mgh[2*c0+6];

    f32x16 acc0 = {}, acc1 = {};

    auto seg = [&](int Q, int cbeg, int cfin, bool lastp) {
        // this quarter's z octets for both tiles
        const char* zq0 = zmb0 + Q * 1024;
        const char* zq1 = zmb1 + Q * 1024;
        float2v zA0, zA1, zA2, zA3, zB0, zB1, zB2, zB3;
        zA0.x = *(const float*)(zq0 +   0); zA0.y = *(const float*)(zq0 + 128);
        zA1.x = *(const float*)(zq0 + 256); zA1.y = *(const float*)(zq0 + 384);
        zA2.x = *(const float*)(zq0 + 512); zA2.y = *(const float*)(zq0 + 640);
        zA3.x = *(const float*)(zq0 + 768); zA3.y = *(const float*)(zq0 + 896);
        zB0.x = *(const float*)(zq1 +   0); zB0.y = *(const float*)(zq1 + 128);
        zB1.x = *(const float*)(zq1 + 256); zB1.y = *(const float*)(zq1 + 384);
        zB2.x = *(const float*)(zq1 + 512); zB2.y = *(const float*)(zq1 + 640);
        zB3.x = *(const float*)(zq1 + 768); zB3.y = *(const float*)(zq1 + 896);

        auto mfma0 = [&](float pp, const uint4& bv) {   // tile0
            float2v p2; p2.x = pp; p2.y = pp;
            union { unsigned u[4]; short8 sv; } a;
            float2v t0 = p2 * zA0; a.u[0] = pack_bf16(t0.x, t0.y);
            float2v t1 = p2 * zA1; a.u[1] = pack_bf16(t1.x, t1.y);
            float2v t2 = p2 * zA2; a.u[2] = pack_bf16(t2.x, t2.y);
            float2v t3 = p2 * zA3; a.u[3] = pack_bf16(t3.x, t3.y);
            union { uint4 v; short8 sv; } b; b.v = bv;
            acc0 = __builtin_amdgcn_mfma_f32_32x32x16_bf16(a.sv, b.sv, acc0, 0, 0, 0);
        };
        auto mfma1 = [&](float pp, const uint4& bv) {   // tile1
            float2v p2; p2.x = pp; p2.y = pp;
            union { unsigned u[4]; short8 sv; } a;
            float2v t0 = p2 * zB0; a.u[0] = pack_bf16(t0.x, t0.y);
            float2v t1 = p2 * zB1; a.u[1] = pack_bf16(t1.x, t1.y);
            float2v t2 = p2 * zB2; a.u[2] = pack_bf16(t2.x, t2.y);
            float2v t3 = p2 * zB3; a.u[3] = pack_bf16(t3.x, t3.y);
            union { uint4 v; short8 sv; } b; b.v = bv;
            acc1 = __builtin_amdgcn_mfma_f32_32x32x16_bf16(a.sv, b.sv, acc1, 0, 0, 0);
        };

        for (int c = cbeg; c < cfin; c += 2) {
            // stage 1: mg for iter+2 (pad absorbs overread)
            unsigned nw0 = mgh[2*c+8], nw1 = mgh[2*c+10];
            // stage 2: z reads for iter+1 from staged words
            float a0i = *(const float*)(zmb0 + (w0s & 0xFFFFu)), a0j = *(const float*)(zmb0 + (w0s >> 16));
            float a1i = *(const float*)(zmb1 + (w0s & 0xFFFFu)), a1j = *(const float*)(zmb1 + (w0s >> 16));
            float b0i = *(const float*)(zmb0 + (w1s & 0xFFFFu)), b0j = *(const float*)(zmb0 + (w1s >> 16));
            float b1i = *(const float*)(zmb1 + (w1s & 0xFFFFu)), b1j = *(const float*)(zmb1 + (w1s >> 16));
            // 4 MFMAs: 2 chunks x 2 tiles, B shared per chunk
            mfma0(pA0, curA); mfma1(pA1, curA);
            mfma0(pB0, curB); mfma1(pB1, curB);
            // retire products + mg
            pA0 = a0i * a0j; pA1 = a1i * a1j; pB0 = b0i * b0j; pB1 = b1i * b1j;
            w0s = nw0; w1s = nw1;
            // rotate B and issue distance-2 load straight into sh (chunks c+4,c+5)
            curA = shA; curB = shB;
            int off = (lastp && c + 4 >= cfin) ? 0 : 256;
            shA = p[off]; shB = p[off + 64];
            p += 128;
        }
    };

    // quarter-aligned pieces of this wave's [c0, c0+138) range
    if (kh == 0)      { seg(0,   0,  36, false); seg(1,  36, 120, false); seg(2, 120, 138, true); }
    else if (kh == 1) { seg(2, 138, 276, true); }
    else if (kh == 2) { seg(2, 276, 280, false); seg(3, 280, 414, true); }
    else              { seg(3, 414, 552, true); }

    // combine: kh1..3 park partials; kh0 reduces + stores both tiles
    if (kh != 0) {
#pragma unroll
        for (int r = 0; r < 16; ++r) {
            int row = (r & 3) + 8 * (r >> 2) + 4 * half;
            cs[kh - 1][0][row][m] = acc0[r];
            cs[kh - 1][1][row][m] = acc1[r];
        }
    }
    __syncthreads();
    if (kh == 0) {
        const float bias = Xi[m] * Xi_mask[m];   // library row 0 (ones), col n = m
        float* o0 = out + R * Z;
        float* o1 = out + (R + 32) * Z;
#pragma unroll
        for (int r = 0; r < 16; ++r) {
            int row = (r & 3) + 8 * (r >> 2) + 4 * half;
            o0[row * Z + m] = acc0[r] + cs[0][0][row][m] + cs[1][0][row][m] + cs[2][0][row][m] + bias;
            o1[row * Z + m] = acc1[r] + cs[0][1][row][m] + cs[1][1][row][m] + cs[2][1][row][m] + bias;
        }
    }
}

extern "C" void kernel_launch(void* const* d_in, const int* in_sizes, int n_in,
                              void* d_out, int out_size, void* d_ws, size_t ws_size,
                              hipStream_t stream) {
    const float* z       = (const float*)d_in[0];
    const float* Xi      = (const float*)d_in[1];
    const float* Xi_mask = (const float*)d_in[2];
    // d_in[3]=z_mean, d_in[4]=z_std: unused by the reference
    float* out = (float*)d_out;
    uint4* Bp  = (uint4*)d_ws;   // NCHUNK*64*16 = 565,248 bytes

    sindy_prep<<<NGRAN / 4, 256, 0, stream>>>(Xi, Xi_mask, (uint2*)d_ws, ws_size);
    sindy_mfma<<<NBLK, 256, 0, stream>>>(z, Xi, Xi_mask, Bp, out);
}

// Round 14
// 122.295 us; speedup vs baseline: 4.2976x; 1.0027x over previous
//
#include <hip/hip_runtime.h>

// SINDy: out[65536,32] = Theta(z)[65536,6545] @ (Xi*Xi_mask)[6545,32]
// Round-14 = R13 (best, 63.7us) + ONE zero-register change:
//  - interleaved z table zs[k][2][32] (tile0/tile1 rows 128 B apart) ->
//    each per-chunk z-gather pair (same offset, both tiles) fuses into one
//    ds_read2_b32 (offset1 = offset0 + 32 dwords). z LDS ops 8 -> 4 per
//    iteration; total LDS pipe ops 10 -> 6 (pipe busy 42% -> ~25%).
//    mg byte offsets rescale x256 (max 8192, fits u16).
// Everything else byte-identical to R13 (distance-2 B rotation, truncation
// pack, split-K x4, 3-stage mg/z staging, combine).
// MFMA 32x32x16_bf16 layouts (verified rounds 1-13):
//   A[m][k]: m=lane&31, k=(lane>>5)*8+jj
//   B[k][n]: n=lane&31, k=(lane>>5)*8+jj
//   C/D:     col=lane&31, row=(reg&3)+8*(reg>>2)+4*(lane>>5)

#define Z 32
#define ROWS 65536
#define NBLK (ROWS / 64)         // 1024 blocks: 2 tiles x 4 k-splits (4 waves)

#define NCHUNK 552               // quarters: 36 + 84 + 160 + 272
#define NGRAN (NCHUNK * 2)
#define NGP 1120                 // padded mg table (overreads -> 0)
#define KSPAN 138                // chunks per k-split (552/4)

typedef short short8 __attribute__((ext_vector_type(8)));
typedef float f32x16 __attribute__((ext_vector_type(16)));
typedef float float2v __attribute__((ext_vector_type(2)));

struct Sched {
    unsigned mg[NGP];          // (i*256) | (j*256)<<16 byte offs into zs[k][2][32]; pad=0
    short rt[NGRAN * 8];       // library row per (granule, jj), -1 = pad
    int nq[4];
};

constexpr Sched make_sched() {
    Sched s{};
    short gi[NGP] = {}, gj[NGP] = {};
    char gt[NGP] = {}, gq[NGP] = {};
    int tidx[32][32] = {}, pidx[32] = {};
    {
        int n = 0;
        for (int a = 0; a < 32; ++a)
            for (int b = a; b < 32; ++b) { tidx[a][b] = n; n += 32 - b; }
        for (int i = 0; i < 32; ++i) pidx[i] = i * 32 - i * (i - 1) / 2;
    }
    int g = 0;
    for (int q = 0; q < 4; ++q) {
        int g0 = g;
        // triples (a<=b): granule covers k in [8q,8q+8) for k>=b -> b>>3 <= q
        for (int b = 0; b < 32; ++b)
            if ((b >> 3) <= q)
                for (int a = 0; a <= b; ++a) { gi[g]=(short)a; gj[g]=(short)b; gt[g]=0; gq[g]=(char)q; ++g; }
        // pairs (b,32): theta = z_b*z_k, valid k<=b -> b>>3 >= q
        for (int b = 0; b < 32; ++b)
            if ((b >> 3) >= q) { gi[g]=(short)b; gj[g]=32; gt[g]=1; gq[g]=(char)q; ++g; }
        // linear: theta = z_k
        gi[g]=32; gj[g]=32; gt[g]=2; gq[g]=(char)q; ++g;
        // pad quarter to a multiple of 8 granules (4 chunks)
        while ((g - g0) & 7) { gi[g]=32; gj[g]=32; gt[g]=3; gq[g]=(char)q; ++g; }
        s.nq[q] = (g - g0) / 2;
    }
    for (int gg = 0; gg < NGRAN; ++gg) {
        s.mg[gg] = ((unsigned)gi[gg] * 256u) | (((unsigned)gj[gg] * 256u) << 16);
        int i = gi[gg], j = gj[gg], ty = gt[gg], q = gq[gg];
        for (int jj = 0; jj < 8; ++jj) {
            int k = 8 * q + jj, row = -1;
            if (ty == 0)      { if (k >= j) row = 561 + tidx[i][j] + (k - j); }   // triple (i,j,k)
            else if (ty == 1) { if (k <= i) row = 33 + pidx[k] + (i - k); }       // pair (k,i)
            else if (ty == 2) { row = 1 + k; }                                    // linear z_k
            s.rt[gg * 8 + jj] = (short)row;
        }
    }
    // [NGRAN,NGP): mg stays 0 -> pipeline overreads hit zs[0][0][m], never used
    return s;
}
constexpr Sched S = make_sched();
static_assert(S.nq[0] == 36 && S.nq[1] == 84 && S.nq[2] == 160 && S.nq[3] == 272, "chunk counts");

// truncation pack: out = hi16(s0) | hi16(s1)<<16 — one v_perm (R11-proven numerics)
__device__ __forceinline__ unsigned pack_bf16(float s0, float s1) {
    return __builtin_amdgcn_perm(__builtin_bit_cast(unsigned, s1),
                                 __builtin_bit_cast(unsigned, s0), 0x07060302u);
}

// ---- prep (R7-proven): coalesced, block per 4 granules; B bf16 stays RNE ----
__global__ void sindy_prep(const float* __restrict__ Xi,
                           const float* __restrict__ Xi_mask,
                           uint2* __restrict__ Bp2, size_t ws_size) {
    __shared__ unsigned short sh[8][32];
    const int tid = threadIdx.x;
    const int jj = tid >> 5, n = tid & 31;
#pragma unroll
    for (int pass = 0; pass < 4; ++pass) {
        int g = blockIdx.x * 4 + pass;
        int row = S.rt[g * 8 + jj];
        float f = 0.0f;
        if (row >= 0) f = Xi[row * Z + n] * Xi_mask[row * Z + n];
        unsigned u = __builtin_bit_cast(unsigned, f);
        sh[jj][n] = (unsigned short)((u + 0x7FFFu + ((u >> 16) & 1u)) >> 16);  // RNE
        __syncthreads();
        if (tid < 64) {
            int n2 = tid & 31, rep = tid >> 5;
            unsigned v0 = sh[4*rep+0][n2], v1 = sh[4*rep+1][n2];
            unsigned v2 = sh[4*rep+2][n2], v3 = sh[4*rep+3][n2];
            int c = g >> 1, h = g & 1;
            size_t idx = ((size_t)c * 64 + h * 32 + n2) * 2 + rep;
            if ((idx + 1) * 8 <= ws_size)
                Bp2[idx] = uint2{v0 | (v1 << 16), v2 | (v3 << 16)};
        }
        __syncthreads();
    }
}

// ---- main: block = 2 tiles x 4 k-splits; wave = BOTH tiles, one k-split ----
__global__ __launch_bounds__(256, 4) void sindy_mfma(const float* __restrict__ z,
                                                     const float* __restrict__ Xi,
                                                     const float* __restrict__ Xi_mask,
                                                     const uint4* __restrict__ Bp,
                                                     float* __restrict__ out) {
    const int lane = threadIdx.x & 63;
    const int kh = threadIdx.x >> 6;     // k-split 0..3
    const int m = lane & 31;
    const int half = lane >> 5;
    const long R = (long)blockIdx.x * 64;   // rows of tile0; tile1 = R+32

    __shared__ float zs[33][2][32];      // interleaved: zs[k][tile][m]; bank = m
    __shared__ float cs[3][2][32][32];   // partials from kh1..3, per tile
    __shared__ unsigned mg_sh[NGP];

    for (int t = threadIdx.x; t < NGP; t += 256) mg_sh[t] = S.mg[t];
    // stage z for 64 rows (coalesced float4 reads)
    for (int idx = threadIdx.x; idx < 512; idx += 256) {
        int row = idx >> 3, q4 = idx & 7;
        float4 v = ((const float4*)(z + (R + row) * Z))[q4];
        int t = row >> 5, mm = row & 31;
        zs[4*q4+0][t][mm] = v.x; zs[4*q4+1][t][mm] = v.y;
        zs[4*q4+2][t][mm] = v.z; zs[4*q4+3][t][mm] = v.w;
    }
    if (threadIdx.x < 64) zs[32][threadIdx.x >> 5][threadIdx.x & 31] = 1.0f;  // z~[32]=1
    __syncthreads();

    const int c0 = kh * KSPAN;
    const char* zmb = (const char*)&zs[0][0][0] + 4 * m;   // tile0; tile1 = +128
    const unsigned* mgh = mg_sh + half;

    // B stream: cur = chunks (c, c+1), sh = chunks (c+2, c+3); loads issued
    // after the MFMA block go straight into sh (distance 2, no extra regs)
    const uint4* p = Bp + lane + (size_t)c0 * 64;
    uint4 curA = p[0], curB = p[64];
    uint4 shA  = p[128], shB = p[192];

    // prime shallow pipeline (plain scalars, single scope — R9/R13-proven)
    unsigned u0 = mgh[2*c0], u1 = mgh[2*c0+2];
    float pA0, pA1, pB0, pB1;
    {
        float i0 = *(const float*)(zmb + (u0 & 0xFFFFu)), i1 = *(const float*)(zmb + (u0 & 0xFFFFu) + 128);
        float j0 = *(const float*)(zmb + (u0 >> 16)),     j1 = *(const float*)(zmb + (u0 >> 16) + 128);
        pA0 = i0 * j0; pA1 = i1 * j1;
        float e0 = *(const float*)(zmb + (u1 & 0xFFFFu)), e1 = *(const float*)(zmb + (u1 & 0xFFFFu) + 128);
        float f0 = *(const float*)(zmb + (u1 >> 16)),     f1 = *(const float*)(zmb + (u1 >> 16) + 128);
        pB0 = e0 * f0; pB1 = e1 * f1;
    }
    unsigned w0s = mgh[2*c0+4], w1s = mgh[2*c0+6];

    f32x16 acc0 = {}, acc1 = {};

    auto seg = [&](int Q, int cbeg, int cfin, bool lastp) {
        // this quarter's z octets for both tiles (k stride now 256 B)
        const char* zq = zmb + Q * 2048;
        float2v zA0, zA1, zA2, zA3, zB0, zB1, zB2, zB3;
        zA0.x = *(const float*)(zq +    0); zB0.x = *(const float*)(zq +  128);
        zA0.y = *(const float*)(zq +  256); zB0.y = *(const float*)(zq +  384);
        zA1.x = *(const float*)(zq +  512); zB1.x = *(const float*)(zq +  640);
        zA1.y = *(const float*)(zq +  768); zB1.y = *(const float*)(zq +  896);
        zA2.x = *(const float*)(zq + 1024); zB2.x = *(const float*)(zq + 1152);
        zA2.y = *(const float*)(zq + 1280); zB2.y = *(const float*)(zq + 1408);
        zA3.x = *(const float*)(zq + 1536); zB3.x = *(const float*)(zq + 1664);
        zA3.y = *(const float*)(zq + 1792); zB3.y = *(const float*)(zq + 1920);

        auto mfma0 = [&](float pp, const uint4& bv) {   // tile0
            float2v p2; p2.x = pp; p2.y = pp;
            union { unsigned u[4]; short8 sv; } a;
            float2v t0 = p2 * zA0; a.u[0] = pack_bf16(t0.x, t0.y);
            float2v t1 = p2 * zA1; a.u[1] = pack_bf16(t1.x, t1.y);
            float2v t2 = p2 * zA2; a.u[2] = pack_bf16(t2.x, t2.y);
            float2v t3 = p2 * zA3; a.u[3] = pack_bf16(t3.x, t3.y);
            union { uint4 v; short8 sv; } b; b.v = bv;
            acc0 = __builtin_amdgcn_mfma_f32_32x32x16_bf16(a.sv, b.sv, acc0, 0, 0, 0);
        };
        auto mfma1 = [&](float pp, const uint4& bv) {   // tile1
            float2v p2; p2.x = pp; p2.y = pp;
            union { unsigned u[4]; short8 sv; } a;
            float2v t0 = p2 * zB0; a.u[0] = pack_bf16(t0.x, t0.y);
            float2v t1 = p2 * zB1; a.u[1] = pack_bf16(t1.x, t1.y);
            float2v t2 = p2 * zB2; a.u[2] = pack_bf16(t2.x, t2.y);
            float2v t3 = p2 * zB3; a.u[3] = pack_bf16(t3.x, t3.y);
            union { uint4 v; short8 sv; } b; b.v = bv;
            acc1 = __builtin_amdgcn_mfma_f32_32x32x16_bf16(a.sv, b.sv, acc1, 0, 0, 0);
        };

        for (int c = cbeg; c < cfin; c += 2) {
            // stage 1: mg for iter+2 (pad absorbs overread)
            unsigned nw0 = mgh[2*c+8], nw1 = mgh[2*c+10];
            // stage 2: z reads for iter+1 — tile pairs 128 B apart -> ds_read2_b32
            float a0i = *(const float*)(zmb + (w0s & 0xFFFFu));
            float a1i = *(const float*)(zmb + (w0s & 0xFFFFu) + 128);
            float a0j = *(const float*)(zmb + (w0s >> 16));
            float a1j = *(const float*)(zmb + (w0s >> 16) + 128);
            float b0i = *(const float*)(zmb + (w1s & 0xFFFFu));
            float b1i = *(const float*)(zmb + (w1s & 0xFFFFu) + 128);
            float b0j = *(const float*)(zmb + (w1s >> 16));
            float b1j = *(const float*)(zmb + (w1s >> 16) + 128);
            // 4 MFMAs: 2 chunks x 2 tiles, B shared per chunk
            mfma0(pA0, curA); mfma1(pA1, curA);
            mfma0(pB0, curB); mfma1(pB1, curB);
            // retire products + mg
            pA0 = a0i * a0j; pA1 = a1i * a1j; pB0 = b0i * b0j; pB1 = b1i * b1j;
            w0s = nw0; w1s = nw1;
            // rotate B and issue distance-2 load straight into sh (chunks c+4,c+5)
            curA = shA; curB = shB;
            int off = (lastp && c + 4 >= cfin) ? 0 : 256;
            shA = p[off]; shB = p[off + 64];
            p += 128;
        }
    };

    // quarter-aligned pieces of this wave's [c0, c0+138) range
    if (kh == 0)      { seg(0,   0,  36, false); seg(1,  36, 120, false); seg(2, 120, 138, true); }
    else if (kh == 1) { seg(2, 138, 276, true); }
    else if (kh == 2) { seg(2, 276, 280, false); seg(3, 280, 414, true); }
    else              { seg(3, 414, 552, true); }

    // combine: kh1..3 park partials; kh0 reduces + stores both tiles
    if (kh != 0) {
#pragma unroll
        for (int r = 0; r < 16; ++r) {
            int row = (r & 3) + 8 * (r >> 2) + 4 * half;
            cs[kh - 1][0][row][m] = acc0[r];
            cs[kh - 1][1][row][m] = acc1[r];
        }
    }
    __syncthreads();
    if (kh == 0) {
        const float bias = Xi[m] * Xi_mask[m];   // library row 0 (ones), col n = m
        float* o0 = out + R * Z;
        float* o1 = out + (R + 32) * Z;
#pragma unroll
        for (int r = 0; r < 16; ++r) {
            int row = (r & 3) + 8 * (r >> 2) + 4 * half;
            o0[row * Z + m] = acc0[r] + cs[0][0][row][m] + cs[1][0][row][m] + cs[2][0][row][m] + bias;
            o1[row * Z + m] = acc1[r] + cs[0][1][row][m] + cs[1][1][row][m] + cs[2][1][row][m] + bias;
        }
    }
}

extern "C" void kernel_launch(void* const* d_in, const int* in_sizes, int n_in,
                              void* d_out, int out_size, void* d_ws, size_t ws_size,
                              hipStream_t stream) {
    const float* z       = (const float*)d_in[0];
    const float* Xi      = (const float*)d_in[1];
    const float* Xi_mask = (const float*)d_in[2];
    // d_in[3]=z_mean, d_in[4]=z_std: unused by the reference
    float* out = (float*)d_out;
    uint4* Bp  = (uint4*)d_ws;   // NCHUNK*64*16 = 565,248 bytes

    sindy_prep<<<NGRAN / 4, 256, 0, stream>>>(Xi, Xi_mask, (uint2*)d_ws, ws_size);
    sindy_mfma<<<NBLK, 256, 0, stream>>>(z, Xi, Xi_mask, Bp, out);
}

// Round 17
// 121.622 us; speedup vs baseline: 4.3214x; 1.0055x over previous
//
#include <hip/hip_runtime.h>

// SINDy: out[65536,32] = Theta(z)[65536,6545] @ (Xi*Xi_mask)[6545,32]
// Round-17 = last DMA attempt, order-independent handshake:
//  - R15/R16 failed with run-varying garbage even under an asm memory fence
//    -> suspect: vmcnt retires OUT OF ORDER for LDS-DMA (m135 only verified
//    in-order drain for global_load->VGPR). vmcnt(2) then proves nothing
//    about the oldest 2 loads.
//  - Fix: pair-granularity DOUBLE BUFFER needing only vmcnt(0): top of iter c
//    issues DMAs for c+2,c+3 (slots of consumed c-2,c-1); bottom waits
//    vmcnt(0) (asm + memory clobber). In-flight = one full iteration body
//    (~500cyc) > L2 latency; "all done" is retirement-order independent.
//  - dma16 now takes the PER-LANE lds pointer (&bring[kh][slot][lane]) —
//    byte-for-byte the m97-verified calling form.
// Everything else identical to R14/R16 (interleaved z, truncation pack,
// split-K x4, mg/z staged pipeline, sequential combine).
// MFMA 32x32x16_bf16 layouts (verified rounds 1-14):
//   A[m][k]: m=lane&31, k=(lane>>5)*8+jj
//   B[k][n]: n=lane&31, k=(lane>>5)*8+jj
//   C/D:     col=lane&31, row=(reg&3)+8*(reg>>2)+4*(lane>>5)

#define Z 32
#define ROWS 65536
#define NBLK (ROWS / 64)         // 1024 blocks: 2 tiles x 4 k-splits (4 waves)

#define NCHUNK 552               // quarters: 36 + 84 + 160 + 272
#define NGRAN (NCHUNK * 2)
#define NGP 1120                 // padded mg table (overreads -> 0)
#define KSPAN 138                // chunks per k-split (552/4)

typedef short short8 __attribute__((ext_vector_type(8)));
typedef float f32x16 __attribute__((ext_vector_type(16)));
typedef float float2v __attribute__((ext_vector_type(2)));

struct Sched {
    unsigned mg[NGP];          // (i*256) | (j*256)<<16 byte offs into zs[k][2][32]; pad=0
    short rt[NGRAN * 8];       // library row per (granule, jj), -1 = pad
    int nq[4];
};

constexpr Sched make_sched() {
    Sched s{};
    short gi[NGP] = {}, gj[NGP] = {};
    char gt[NGP] = {}, gq[NGP] = {};
    int tidx[32][32] = {}, pidx[32] = {};
    {
        int n = 0;
        for (int a = 0; a < 32; ++a)
            for (int b = a; b < 32; ++b) { tidx[a][b] = n; n += 32 - b; }
        for (int i = 0; i < 32; ++i) pidx[i] = i * 32 - i * (i - 1) / 2;
    }
    int g = 0;
    for (int q = 0; q < 4; ++q) {
        int g0 = g;
        // triples (a<=b): granule covers k in [8q,8q+8) for k>=b -> b>>3 <= q
        for (int b = 0; b < 32; ++b)
            if ((b >> 3) <= q)
                for (int a = 0; a <= b; ++a) { gi[g]=(short)a; gj[g]=(short)b; gt[g]=0; gq[g]=(char)q; ++g; }
        // pairs (b,32): theta = z_b*z_k, valid k<=b -> b>>3 >= q
        for (int b = 0; b < 32; ++b)
            if ((b >> 3) >= q) { gi[g]=(short)b; gj[g]=32; gt[g]=1; gq[g]=(char)q; ++g; }
        // linear: theta = z_k
        gi[g]=32; gj[g]=32; gt[g]=2; gq[g]=(char)q; ++g;
        // pad quarter to a multiple of 8 granules (4 chunks)
        while ((g - g0) & 7) { gi[g]=32; gj[g]=32; gt[g]=3; gq[g]=(char)q; ++g; }
        s.nq[q] = (g - g0) / 2;
    }
    for (int gg = 0; gg < NGRAN; ++gg) {
        s.mg[gg] = ((unsigned)gi[gg] * 256u) | (((unsigned)gj[gg] * 256u) << 16);
        int i = gi[gg], j = gj[gg], ty = gt[gg], q = gq[gg];
        for (int jj = 0; jj < 8; ++jj) {
            int k = 8 * q + jj, row = -1;
            if (ty == 0)      { if (k >= j) row = 561 + tidx[i][j] + (k - j); }   // triple (i,j,k)
            else if (ty == 1) { if (k <= i) row = 33 + pidx[k] + (i - k); }       // pair (k,i)
            else if (ty == 2) { row = 1 + k; }                                    // linear z_k
            s.rt[gg * 8 + jj] = (short)row;
        }
    }
    // [NGRAN,NGP): mg stays 0 -> pipeline overreads hit zs[0][0][m], never used
    return s;
}
constexpr Sched S = make_sched();
static_assert(S.nq[0] == 36 && S.nq[1] == 84 && S.nq[2] == 160 && S.nq[3] == 272, "chunk counts");

// truncation pack: out = hi16(s0) | hi16(s1)<<16 — one v_perm (R11-proven numerics)
__device__ __forceinline__ unsigned pack_bf16(float s0, float s1) {
    return __builtin_amdgcn_perm(__builtin_bit_cast(unsigned, s1),
                                 __builtin_bit_cast(unsigned, s0), 0x07060302u);
}

// async global->LDS: per-lane gptr AND per-lane lds_ptr (m97-verified form;
// HW semantics: wave-uniform base + lane*16 — our layout matches exactly)
__device__ __forceinline__ void dma16(const uint4* g, uint4* lds_lane) {
    __builtin_amdgcn_global_load_lds(
        (const __attribute__((address_space(1))) unsigned*)g,
        (__attribute__((address_space(3))) unsigned*)lds_lane, 16, 0, 0);
}

// full drain — retirement-order independent; memory clobber = compiler fence
__device__ __forceinline__ void wait_vm0() {
    asm volatile("s_waitcnt vmcnt(0)" ::: "memory");
}

// ---- prep (R7-proven): coalesced, block per 4 granules; B bf16 stays RNE ----
__global__ void sindy_prep(const float* __restrict__ Xi,
                           const float* __restrict__ Xi_mask,
                           uint2* __restrict__ Bp2, size_t ws_size) {
    __shared__ unsigned short sh[8][32];
    const int tid = threadIdx.x;
    const int jj = tid >> 5, n = tid & 31;
#pragma unroll
    for (int pass = 0; pass < 4; ++pass) {
        int g = blockIdx.x * 4 + pass;
        int row = S.rt[g * 8 + jj];
        float f = 0.0f;
        if (row >= 0) f = Xi[row * Z + n] * Xi_mask[row * Z + n];
        unsigned u = __builtin_bit_cast(unsigned, f);
        sh[jj][n] = (unsigned short)((u + 0x7FFFu + ((u >> 16) & 1u)) >> 16);  // RNE
        __syncthreads();
        if (tid < 64) {
            int n2 = tid & 31, rep = tid >> 5;
            unsigned v0 = sh[4*rep+0][n2], v1 = sh[4*rep+1][n2];
            unsigned v2 = sh[4*rep+2][n2], v3 = sh[4*rep+3][n2];
            int c = g >> 1, h = g & 1;
            size_t idx = ((size_t)c * 64 + h * 32 + n2) * 2 + rep;
            if ((idx + 1) * 8 <= ws_size)
                Bp2[idx] = uint2{v0 | (v1 << 16), v2 | (v3 << 16)};
        }
        __syncthreads();
    }
}

// ---- main: block = 2 tiles x 4 k-splits; wave = BOTH tiles, one k-split ----
__global__ __launch_bounds__(256, 4) void sindy_mfma(const float* __restrict__ z,
                                                     const float* __restrict__ Xi,
                                                     const float* __restrict__ Xi_mask,
                                                     const uint4* __restrict__ Bp,
                                                     float* __restrict__ out) {
    const int lane = threadIdx.x & 63;
    const int kh = threadIdx.x >> 6;     // k-split 0..3 (= wave id)
    const int m = lane & 31;
    const int half = lane >> 5;
    const long R = (long)blockIdx.x * 64;   // rows of tile0; tile1 = R+32

    __shared__ float zs[33][2][32];      // interleaved: zs[k][tile][m]; bank = m
    __shared__ float cs[2][32][32];      // sequential-add combine (2 tiles)
    __shared__ unsigned mg_sh[NGP];
    __shared__ uint4 bring[4][4][64];    // [wave][slot][lane] B ring, 16 KB

    for (int t = threadIdx.x; t < NGP; t += 256) mg_sh[t] = S.mg[t];
    // stage z for 64 rows (coalesced float4 reads)
    for (int idx = threadIdx.x; idx < 512; idx += 256) {
        int row = idx >> 3, q4 = idx & 7;
        float4 v = ((const float4*)(z + (R + row) * Z))[q4];
        int t = row >> 5, mm = row & 31;
        zs[4*q4+0][t][mm] = v.x; zs[4*q4+1][t][mm] = v.y;
        zs[4*q4+2][t][mm] = v.z; zs[4*q4+3][t][mm] = v.w;
    }
    if (threadIdx.x < 64) zs[32][threadIdx.x >> 5][threadIdx.x & 31] = 1.0f;  // z~[32]=1
    __syncthreads();

    const int c0 = kh * KSPAN;
    const char* zmb = (const char*)&zs[0][0][0] + 4 * m;   // tile0; tile1 = +128
    const unsigned* mgh = mg_sh + half;
    const uint4* bpl = Bp + lane;

    // prologue: DMA chunks c0, c0+1; full drain before first consumption
    dma16(bpl + (size_t)(c0+0) * 64, &bring[kh][(c0+0) & 3][lane]);
    dma16(bpl + (size_t)(c0+1) * 64, &bring[kh][(c0+1) & 3][lane]);
    wait_vm0();

    // prime shallow pipeline (plain scalars, single scope — R9/R13-proven)
    unsigned u0 = mgh[2*c0], u1 = mgh[2*c0+2];
    float pA0, pA1, pB0, pB1;
    {
        float i0 = *(const float*)(zmb + (u0 & 0xFFFFu)), i1 = *(const float*)(zmb + (u0 & 0xFFFFu) + 128);
        float j0 = *(const float*)(zmb + (u0 >> 16)),     j1 = *(const float*)(zmb + (u0 >> 16) + 128);
        pA0 = i0 * j0; pA1 = i1 * j1;
        float e0 = *(const float*)(zmb + (u1 & 0xFFFFu)), e1 = *(const float*)(zmb + (u1 & 0xFFFFu) + 128);
        float f0 = *(const float*)(zmb + (u1 >> 16)),     f1 = *(const float*)(zmb + (u1 >> 16) + 128);
        pB0 = e0 * f0; pB1 = e1 * f1;
    }
    unsigned w0s = mgh[2*c0+4], w1s = mgh[2*c0+6];

    f32x16 acc0 = {}, acc1 = {};

    auto seg = [&](int Q, int cbeg, int cfin) {
        // this quarter's z octets for both tiles (k stride 256 B)
        const char* zq = zmb + Q * 2048;
        float2v zA0, zA1, zA2, zA3, zB0, zB1, zB2, zB3;
        zA0.x = *(const float*)(zq +    0); zB0.x = *(const float*)(zq +  128);
        zA0.y = *(const float*)(zq +  256); zB0.y = *(const float*)(zq +  384);
        zA1.x = *(const float*)(zq +  512); zB1.x = *(const float*)(zq +  640);
        zA1.y = *(const float*)(zq +  768); zB1.y = *(const float*)(zq +  896);
        zA2.x = *(const float*)(zq + 1024); zB2.x = *(const float*)(zq + 1152);
        zA2.y = *(const float*)(zq + 1280); zB2.y = *(const float*)(zq + 1408);
        zA3.x = *(const float*)(zq + 1536); zB3.x = *(const float*)(zq + 1664);
        zA3.y = *(const float*)(zq + 1792); zB3.y = *(const float*)(zq + 1920);

        auto mfma0 = [&](float pp, const uint4& bv) {   // tile0
            float2v p2; p2.x = pp; p2.y = pp;
            union { unsigned u[4]; short8 sv; } a;
            float2v t0 = p2 * zA0; a.u[0] = pack_bf16(t0.x, t0.y);
            float2v t1 = p2 * zA1; a.u[1] = pack_bf16(t1.x, t1.y);
            float2v t2 = p2 * zA2; a.u[2] = pack_bf16(t2.x, t2.y);
            float2v t3 = p2 * zA3; a.u[3] = pack_bf16(t3.x, t3.y);
            union { uint4 v; short8 sv; } b; b.v = bv;
            acc0 = __builtin_amdgcn_mfma_f32_32x32x16_bf16(a.sv, b.sv, acc0, 0, 0, 0);
        };
        auto mfma1 = [&](float pp, const uint4& bv) {   // tile1
            float2v p2; p2.x = pp; p2.y = pp;
            union { unsigned u[4]; short8 sv; } a;
            float2v t0 = p2 * zB0; a.u[0] = pack_bf16(t0.x, t0.y);
            float2v t1 = p2 * zB1; a.u[1] = pack_bf16(t1.x, t1.y);
            float2v t2 = p2 * zB2; a.u[2] = pack_bf16(t2.x, t2.y);
            float2v t3 = p2 * zB3; a.u[3] = pack_bf16(t3.x, t3.y);
            union { uint4 v; short8 sv; } b; b.v = bv;
            acc1 = __builtin_amdgcn_mfma_f32_32x32x16_bf16(a.sv, b.sv, acc1, 0, 0, 0);
        };

        for (int c = cbeg; c < cfin; c += 2) {
            // top: issue DMAs for the NEXT pair (c+2, c+3) into the slots that
            // held the pair consumed last iteration (c-2, c-1). Clamped at the
            // table end (those slots are never read).
            int l2 = c + 2, l3 = c + 3;
            int s2 = l2 < NCHUNK ? l2 : NCHUNK - 1;
            int s3 = l3 < NCHUNK ? l3 : NCHUNK - 1;
            dma16(bpl + (size_t)s2 * 64, &bring[kh][l2 & 3][lane]);
            dma16(bpl + (size_t)s3 * 64, &bring[kh][l3 & 3][lane]);
            // current pair: landed (vmcnt(0) at the bottom of last iteration)
            uint4 bA = bring[kh][c & 3][lane];
            uint4 bB = bring[kh][(c + 1) & 3][lane];
            // stage 1: mg for iter+2 (pad absorbs overread)
            unsigned nw0 = mgh[2*c+8], nw1 = mgh[2*c+10];
            // stage 2: z reads for iter+1 — tile pairs 128 B apart (ds_read2)
            float a0i = *(const float*)(zmb + (w0s & 0xFFFFu));
            float a1i = *(const float*)(zmb + (w0s & 0xFFFFu) + 128);
            float a0j = *(const float*)(zmb + (w0s >> 16));
            float a1j = *(const float*)(zmb + (w0s >> 16) + 128);
            float b0i = *(const float*)(zmb + (w1s & 0xFFFFu));
            float b1i = *(const float*)(zmb + (w1s & 0xFFFFu) + 128);
            float b0j = *(const float*)(zmb + (w1s >> 16));
            float b1j = *(const float*)(zmb + (w1s >> 16) + 128);
            // 4 MFMAs: 2 chunks x 2 tiles, B shared per chunk
            mfma0(pA0, bA); mfma1(pA1, bA);
            mfma0(pB0, bB); mfma1(pB1, bB);
            // retire products + mg
            pA0 = a0i * a0j; pA1 = a1i * a1j; pB0 = b0i * b0j; pB1 = b1i * b1j;
            w0s = nw0; w1s = nw1;
            // bottom: full drain — next pair guaranteed in LDS, any order
            wait_vm0();
        }
    };

    // quarter-aligned pieces of this wave's [c0, c0+138) range
    if (kh == 0)      { seg(0,   0,  36); seg(1,  36, 120); seg(2, 120, 138); }
    else if (kh == 1) { seg(2, 138, 276); }
    else if (kh == 2) { seg(2, 276, 280); seg(3, 280, 414); }
    else              { seg(3, 414, 552); }

    // sequential-add combine: kh3 writes, kh2/kh1 add, kh0 finishes
    if (kh == 3) {
#pragma unroll
        for (int r = 0; r < 16; ++r) {
            int row = (r & 3) + 8 * (r >> 2) + 4 * half;
            cs[0][row][m] = acc0[r]; cs[1][row][m] = acc1[r];
        }
    }
    __syncthreads();
    if (kh == 2) {
#pragma unroll
        for (int r = 0; r < 16; ++r) {
            int row = (r & 3) + 8 * (r >> 2) + 4 * half;
            cs[0][row][m] += acc0[r]; cs[1][row][m] += acc1[r];
        }
    }
    __syncthreads();
    if (kh == 1) {
#pragma unroll
        for (int r = 0; r < 16; ++r) {
            int row = (r & 3) + 8 * (r >> 2) + 4 * half;
            cs[0][row][m] += acc0[r]; cs[1][row][m] += acc1[r];
        }
    }
    __syncthreads();
    if (kh == 0) {
        const float bias = Xi[m] * Xi_mask[m];   // library row 0 (ones), col n = m
        float* o0 = out + R * Z;
        float* o1 = out + (R + 32) * Z;
#pragma unroll
        for (int r = 0; r < 16; ++r) {
            int row = (r & 3) + 8 * (r >> 2) + 4 * half;
            o0[row * Z + m] = acc0[r] + cs[0][row][m] + bias;
            o1[row * Z + m] = acc1[r] + cs[1][row][m] + bias;
        }
    }
}

extern "C" void kernel_launch(void* const* d_in, const int* in_sizes, int n_in,
                              void* d_out, int out_size, void* d_ws, size_t ws_size,
                              hipStream_t stream) {
    const float* z       = (const float*)d_in[0];
    const float* Xi      = (const float*)d_in[1];
    const float* Xi_mask = (const float*)d_in[2];
    // d_in[3]=z_mean, d_in[4]=z_std: unused by the reference
    float* out = (float*)d_out;
    uint4* Bp  = (uint4*)d_ws;   // NCHUNK*64*16 = 565,248 bytes

    sindy_prep<<<NGRAN / 4, 256, 0, stream>>>(Xi, Xi_mask, (uint2*)d_ws, ws_size);
    sindy_mfma<<<NBLK, 256, 0, stream>>>(z, Xi, Xi_mask, Bp, out);
}